// Round 6
// baseline (67.875 us; speedup 1.0000x reference)
//
#include <hip/hip_runtime.h>
#include <math.h>

#define S 256
#define H 1024
#define NTAG 20
#define NPAIR 32640  // S*(S-1)/2

// ---- workspace layout (float indices) ----
#define WS_T     0          // [8 kc][256 s][1024 c] score GEMM partials (8 MB)
#define WS_HP    2097152    // [8 kc][3 p][256 s][20 t] hw partials (480 KB)
#define WS_A     2220032    // [256] raw scores (pre-b2)
#define WS_ZC    2220544    // [257]
#define WS_HW0   2220804    // [256*20] (16B-aligned)
#define WS_HW1   2225924    // [256*20]
#define WS_HW2   2231044    // [256*20]
#define WS_PW    2236164    // [257*20]
#define WS_LW    2241304    // [257*20] indexed by L=j-i+1 in [2,256]
#define WS_LOSSP 2246444    // [255]
#define WS_RUN   2246700    // int[256]
#define WS_START 2246956    // int[256]
#define WS_END   2247212    // int[256]
#define WS_CTR   2247468    // int ticket for K2 (zeroed by K1)
#define WS_CTR2  2247469    // int ticket for K3 (zeroed by K2)

// ============ K1: score partials (SGPR-h broadcast) + hw partials ============
// b<256:  score. rg=b&31 (rows rg*8..+7), kc=b>>5 (k chunk of 128).
//         512 threads, thread owns cols {2tid, 2tid+1}, 8-row accumulator.
//         h[r][k] is block-uniform -> compiler emits s_load (SGPR operand);
//         per k-step: 1 coalesced float2 VMEM + 16 wave-FMA. No LDS.
// b>=256: hw partials (rg=hb&15, kc=hb>>3? no: hb>>4), threads 0..255 stage,
//         0..239 compute. Identical math to R5's verified path.
__global__ __launch_bounds__(512) void K1(const float* __restrict__ hidden,
                                          const float* __restrict__ w1,
                                          const float* __restrict__ fcw,
                                          float* __restrict__ ws) {
    const int tid = threadIdx.x;
    const int b = blockIdx.x;
    if (b == 0 && tid == 0) ((int*)ws)[WS_CTR] = 0;   // ticket for K2

    if (b < 256) {
        const int rg = b & 31, kc = b >> 5;
        float2 acc[8];
        #pragma unroll
        for (int r = 0; r < 8; r++) acc[r] = make_float2(0.f, 0.f);

        const float* wp = w1 + (size_t)(kc * 128) * H + tid * 2;
        const float* hp = hidden + (size_t)(rg * 8) * H + kc * 128;  // uniform base

        #pragma unroll 8
        for (int k = 0; k < 128; k++) {
            const float2 wv = *(const float2*)&wp[(size_t)k * H];
            #pragma unroll
            for (int r = 0; r < 8; r++) {
                const float hv = hp[(size_t)r * H + k];   // block-uniform -> s_load
                acc[r].x = fmaf(hv, wv.x, acc[r].x);
                acc[r].y = fmaf(hv, wv.y, acc[r].y);
            }
        }
        float* op = ws + WS_T + (size_t)kc * (S * H) + (size_t)(rg * 8) * H + tid * 2;
        #pragma unroll
        for (int r = 0; r < 8; r++) *(float2*)&op[(size_t)r * H] = acc[r];
    } else {
        __shared__ __align__(16) float shHT[128][20];
        const int hb = b - 256;
        const int rg = hb & 15, kc = hb >> 4;
        if (tid < 256) {
            const int c = tid & 127, rr = tid >> 7;
            #pragma unroll
            for (int e = 0; e < 8; e++) {
                const int r = e * 2 + rr;
                shHT[c][r] = hidden[(rg * 16 + r) * H + kc * 128 + c];
            }
        }
        __syncthreads();
        if (tid < 240) {
            const int t = tid % 20, g = tid / 20;   // g 0..11
            const int p = g >> 2, rsub = g & 3;     // p 0..2, rows rsub*4..+3
            const float* fw = fcw + (size_t)(p * H + kc * 128) * 20 + t;
            float a0 = 0.f, a1 = 0.f, a2 = 0.f, a3 = 0.f;
            #pragma unroll 8
            for (int k = 0; k < 128; k++) {
                const float w = fw[k * 20];
                const float4 h4 = *(const float4*)&shHT[k][rsub * 4];
                a0 = fmaf(h4.x, w, a0);
                a1 = fmaf(h4.y, w, a1);
                a2 = fmaf(h4.z, w, a2);
                a3 = fmaf(h4.w, w, a3);
            }
            float* hpo = ws + WS_HP + ((size_t)(kc * 3 + p) * 256 + rg * 16 + rsub * 4) * 20 + t;
            hpo[0] = a0; hpo[20] = a1; hpo[40] = a2; hpo[60] = a3;
        }
    }
}

// ============ K2: slab reduce + tanh + w2 dot + hw reduce; last block: scans ============
__global__ __launch_bounds__(256) void K2(const float* __restrict__ b1,
                                          const float* __restrict__ w2,
                                          const float* __restrict__ b2,
                                          const int* __restrict__ target,
                                          const float* __restrict__ lenemb,
                                          const float* __restrict__ fcw,
                                          float* __restrict__ ws) {
    const int b = blockIdx.x, tid = threadIdx.x;
    __shared__ float sred[256];
    __shared__ int sticket;
    if (b == 0 && tid == 0) ((int*)ws)[WS_CTR2] = 0;   // ticket for K3

    // --- per-row: sum 8 slabs over 4 cols/thread, fast-tanh, dot w2 ---
    {
        const int c = tid * 4;
        float4 sum = make_float4(0.f, 0.f, 0.f, 0.f);
        #pragma unroll
        for (int kcz = 0; kcz < 8; kcz++) {
            const float4 tv = *(const float4*)&ws[WS_T + (size_t)kcz * (S * H) + (size_t)b * H + c];
            sum.x += tv.x; sum.y += tv.y; sum.z += tv.z; sum.w += tv.w;
        }
        const float4 b4 = *(const float4*)&b1[c];
        const float4 w4 = *(const float4*)&w2[c];
        float lacc = 0.f;
        {
            const float x = fminf(fmaxf(sum.x + b4.x, -15.f), 15.f);
            const float ex = __expf(2.f * x); lacc += ((ex - 1.f) / (ex + 1.f)) * w4.x;
        }
        {
            const float x = fminf(fmaxf(sum.y + b4.y, -15.f), 15.f);
            const float ex = __expf(2.f * x); lacc += ((ex - 1.f) / (ex + 1.f)) * w4.y;
        }
        {
            const float x = fminf(fmaxf(sum.z + b4.z, -15.f), 15.f);
            const float ex = __expf(2.f * x); lacc += ((ex - 1.f) / (ex + 1.f)) * w4.z;
        }
        {
            const float x = fminf(fmaxf(sum.w + b4.w, -15.f), 15.f);
            const float ex = __expf(2.f * x); lacc += ((ex - 1.f) / (ex + 1.f)) * w4.w;
        }
        sred[tid] = lacc;
    }
    __syncthreads();
    for (int off = 128; off > 0; off >>= 1) {
        if (tid < off) sred[tid] += sred[tid + off];
        __syncthreads();
    }
    if (tid == 0) ws[WS_A + b] = sred[0];

    if (tid < 60) {
        const int t = tid % 20, p = tid / 20;
        float s = 0.f;
        #pragma unroll
        for (int kc = 0; kc < 8; kc++)
            s += ws[WS_HP + ((size_t)(kc * 3 + p) * 256 + b) * 20 + t];
        const int base = (p == 0) ? WS_HW0 : (p == 1) ? WS_HW1 : WS_HW2;
        ws[base + b * 20 + t] = s;
    }

    // --- arrival ticket; last block performs all the scan work ---
    __threadfence();
    __syncthreads();
    if (tid == 0) sticket = atomicAdd((int*)ws + WS_CTR, 1);
    __syncthreads();
    if (sticket != 255) return;
    __threadfence();

    {
        const int s = tid;
        __shared__ float shf[256], she[256];
        __shared__ int shi[256], shtg[256];
        __shared__ float shlen[2550];   // lenemb rows 2..256
        __shared__ float shfct[200];    // fcw rows 3072..3081
        __shared__ float shw0[5120];
        __shared__ float shpw[5120];
        __shared__ float soff[4][20];

        for (int idx = s; idx < 2550; idx += 256) shlen[idx] = lenemb[20 + idx];
        if (s < 200) shfct[s] = fcw[61440 + s];
        for (int idx = s; idx < 5120; idx += 256) shw0[idx] = ws[WS_HW0 + idx];

        shtg[s] = target[s];
        const float a = ws[WS_A + s] + b2[0];
        shf[s] = a;
        __syncthreads();

        // lw table from LDS
        for (int item = s; item < 5100; item += 256) {
            const int L2i = item / 20, t = item % 20;   // L = L2i + 2
            float v = 0.f;
            #pragma unroll
            for (int d = 0; d < 10; d++)
                v = fmaf(shlen[L2i * 10 + d], shfct[d * 20 + t], v);
            ws[WS_LW + (L2i + 2) * 20 + t] = v;
        }

        for (int off = 128; off > 0; off >>= 1) {
            if (s < off) shf[s] = fmaxf(shf[s], shf[s + off]);
            __syncthreads();
        }
        const float mx = shf[0];
        __syncthreads();
        const float ev = __expf(a - mx);
        she[s] = ev;
        shf[s] = ev;
        const int chg = (s == 0) ? 1 : (shtg[s] != shtg[s - 1]);
        shi[s] = chg;
        __syncthreads();
        for (int off = 1; off < 256; off <<= 1) {
            const float fv = (s >= off) ? shf[s - off] : 0.f;
            const int   iv = (s >= off) ? shi[s - off] : 0;
            __syncthreads();
            shf[s] += fv;
            shi[s] += iv;
            __syncthreads();
        }
        ws[WS_ZC + s + 1] = shf[s];
        if (s == 0) ws[WS_ZC] = 0.f;
        ((int*)ws)[WS_RUN + s]   = shi[s];
        ((int*)ws)[WS_START + s] = chg;
        ((int*)ws)[WS_END + s]   = (s == 255) ? 1 : (shtg[s] != shtg[s + 1]);

        // segmented Pw scan: 80 lanes, 64-step chains + offset fixup
        if (s < 80) {
            const int t = s % 20, seg = s / 20;
            const int base = seg * 64;
            float pw = 0.f;
            for (int k = 0; k < 64; k++) {
                pw = fmaf(she[base + k], shw0[(base + k) * 20 + t], pw);
                shpw[(base + k) * 20 + t] = pw;
            }
        }
        __syncthreads();
        if (s < 20) {
            const float T0 = shpw[63 * 20 + s], T1 = shpw[127 * 20 + s], T2 = shpw[191 * 20 + s];
            soff[0][s] = 0.f; soff[1][s] = T0; soff[2][s] = T0 + T1; soff[3][s] = T0 + T1 + T2;
        }
        __syncthreads();
        for (int item = s; item < 5140; item += 256) {
            const int r = item / 20, t = item % 20;
            const float v = (r == 0) ? 0.f : shpw[(r - 1) * 20 + t] + soff[(r - 1) >> 6][t];
            ws[WS_PW + item] = v;
        }
    }
}

// ============ K3: pairs (255 blocks x 128 = 32640 exactly) + last-block loss ============
__global__ __launch_bounds__(128) void K3(const int* __restrict__ target,
                                          const float* __restrict__ fcb,
                                          float* __restrict__ out,
                                          float* __restrict__ ws) {
    const int tid = threadIdx.x;
    const int p = blockIdx.x * 128 + tid;
    __shared__ float sred[128];
    __shared__ int sticket;
    float lossacc = 0.f;
    {
        // p = i*255 - i(i-1)/2 + (j-i-1); exact in fp32 for this range.
        int i = (int)((511.0f - sqrtf((float)(261121 - 8 * p))) * 0.5f);
        while ((i + 1) * (510 - i) <= 2 * p) ++i;
        while (i > 0 && i * (511 - i) > 2 * p) --i;
        const int j = p - i * (511 - i) / 2 + i + 1;

        const float Zci  = ws[WS_ZC + i];
        const float invz = 1.f / (ws[WS_ZC + j + 1] - Zci);
        const int L = j - i + 1;
        const int* runid = (const int*)ws + WS_RUN;
        const int* stA   = (const int*)ws + WS_START;
        const int* enA   = (const int*)ws + WS_END;
        const int lbl = (runid[i] == runid[j] && stA[i] && enA[j]) ? target[j] : 0;

        const float4* pwj4 = (const float4*)(ws + WS_PW + (j + 1) * 20);
        const float4* pwi4 = (const float4*)(ws + WS_PW + i * 20);
        const float4* h14  = (const float4*)(ws + WS_HW1 + i * 20);
        const float4* h24  = (const float4*)(ws + WS_HW2 + j * 20);
        const float4* lw4  = (const float4*)(ws + WS_LW + L * 20);
        const float4* fb4  = (const float4*)fcb;
        float4* op4 = (float4*)(out + (size_t)p * 20);

        float lg[20];
        float mx = -1e30f, chosen = 0.f;
        #pragma unroll
        for (int q = 0; q < 5; q++) {
            const float4 aj = pwj4[q], ai = pwi4[q];
            const float4 bi = h14[q],  bj = h24[q];
            const float4 cl = lw4[q],  fb = fb4[q];
            float4 r;
            r.x = (aj.x - ai.x) * invz + bi.x + bj.x + cl.x + fb.x;
            r.y = (aj.y - ai.y) * invz + bi.y + bj.y + cl.y + fb.y;
            r.z = (aj.z - ai.z) * invz + bi.z + bj.z + cl.z + fb.z;
            r.w = (aj.w - ai.w) * invz + bi.w + bj.w + cl.w + fb.w;
            op4[q] = r;
            lg[q * 4 + 0] = r.x; lg[q * 4 + 1] = r.y;
            lg[q * 4 + 2] = r.z; lg[q * 4 + 3] = r.w;
            mx = fmaxf(mx, fmaxf(fmaxf(r.x, r.y), fmaxf(r.z, r.w)));
            chosen = (q * 4 + 0 == lbl) ? r.x : chosen;
            chosen = (q * 4 + 1 == lbl) ? r.y : chosen;
            chosen = (q * 4 + 2 == lbl) ? r.z : chosen;
            chosen = (q * 4 + 3 == lbl) ? r.w : chosen;
        }
        float se = 0.f;
        #pragma unroll
        for (int t = 0; t < 20; t++) se += __expf(lg[t] - mx);
        lossacc = -(chosen - mx - __logf(se));
    }
    sred[tid] = lossacc;
    __syncthreads();
    for (int off = 64; off > 0; off >>= 1) {
        if (tid < off) sred[tid] += sred[tid + off];
        __syncthreads();
    }
    if (tid == 0) ws[WS_LOSSP + blockIdx.x] = sred[0];

    __threadfence();
    __syncthreads();
    if (tid == 0) sticket = atomicAdd((int*)ws + WS_CTR2, 1);
    __syncthreads();
    if (sticket != 254) return;
    __threadfence();
    sred[tid] = ws[WS_LOSSP + tid] + ((tid < 127) ? ws[WS_LOSSP + tid + 128] : 0.f);
    __syncthreads();
    for (int off = 64; off > 0; off >>= 1) {
        if (tid < off) sred[tid] += sred[tid + off];
        __syncthreads();
    }
    if (tid == 0) out[(size_t)NPAIR * 20] = sred[0] / (float)NPAIR;
}

extern "C" void kernel_launch(void* const* d_in, const int* in_sizes, int n_in,
                              void* d_out, int out_size, void* d_ws, size_t ws_size,
                              hipStream_t stream) {
    (void)in_sizes; (void)n_in; (void)out_size; (void)ws_size;
    const float* hidden = (const float*)d_in[0];
    const int*   target = (const int*)d_in[1];
    const float* w1     = (const float*)d_in[2];
    const float* b1     = (const float*)d_in[3];
    const float* w2     = (const float*)d_in[4];
    const float* b2     = (const float*)d_in[5];
    const float* lenemb = (const float*)d_in[6];
    const float* fcw    = (const float*)d_in[7];
    const float* fcb    = (const float*)d_in[8];
    float* out = (float*)d_out;
    float* ws  = (float*)d_ws;

    K1<<<384, 512, 0, stream>>>(hidden, w1, fcw, ws);
    K2<<<256, 256, 0, stream>>>(b1, w2, b2, target, lenemb, fcw, ws);
    K3<<<255, 128, 0, stream>>>(target, fcb, out, ws);
}